// Round 10
// baseline (313.603 us; speedup 1.0000x reference)
//
#include <hip/hip_runtime.h>

#define DIM 512
#define DIM2 1024
#define NGRAPH 512
#define LN_EPS 1e-5f
#define TPB 256
#define NB 2048      // chunk count for segsum/resid; rpb = ceil(200000/2048) = 98
#define RPBMAX 257   // LDS bi-cache capacity (rpb must be <= this)

typedef float f4 __attribute__((ext_vector_type(4)));

__device__ __forceinline__ void nts(f4* p, f4 v) { __builtin_nontemporal_store(v, p); }

// ---------------------------------------------------------------------------
// K1: segment sums. Per block: coalesced prefetch of bi[r0..r1) into LDS,
// run detection via LDS binary search (broadcast reads), branchless 16-row
// inner loop (8 independent 16B loads in flight/lane, ~64 VGPR -> full occ).
// Cached x reads seed L3 for K5. One atomic flush per run.
// ---------------------------------------------------------------------------
__global__ __launch_bounds__(TPB) void segsum_kernel(const f4* __restrict__ x4,
                                                     const int* __restrict__ bi,
                                                     float* __restrict__ sums,
                                                     int n_nodes, int rpb) {
    __shared__ int bis[RPBMAX];
    const int blk = blockIdx.x, t = threadIdx.x;
    const int r0 = blk * rpb;
    const int r1 = min(n_nodes, r0 + rpb);
    const int n = r1 - r0;
    if (n <= 0) return;
    for (int i = t; i < n; i += TPB) bis[i] = bi[r0 + i];
    __syncthreads();

    const int par = t >> 7, c = t & 127;   // 2 rows x 128 f4-cols
    int cur = 0;
    while (cur < n) {
        const int g = bis[cur];
        int lo = cur + 1, hi = n;
        while (lo < hi) {                   // run end via LDS (broadcast)
            int mid = (lo + hi) >> 1;
            if (bis[mid] <= g) lo = mid + 1; else hi = mid;
        }
        const int send = lo;

        f4 a0={0,0,0,0}, a1={0,0,0,0}, a2={0,0,0,0}, a3={0,0,0,0};
        f4 a4={0,0,0,0}, a5={0,0,0,0}, a6={0,0,0,0}, a7={0,0,0,0};
        int r = cur;
        for (; r + 16 <= send; r += 16) {
            const size_t b = (size_t)(r0 + r + par) * 128 + c;
            f4 v0 = x4[b];        f4 v1 = x4[b + 256];
            f4 v2 = x4[b + 512];  f4 v3 = x4[b + 768];
            f4 v4 = x4[b + 1024]; f4 v5 = x4[b + 1280];
            f4 v6 = x4[b + 1536]; f4 v7 = x4[b + 1792];
            a0 += v0; a1 += v1; a2 += v2; a3 += v3;
            a4 += v4; a5 += v5; a6 += v6; a7 += v7;
        }
        for (int rr = r + par; rr < send; rr += 2)
            a0 += x4[(size_t)(r0 + rr) * 128 + c];

        a0 += a1 + a2 + a3 + a4 + a5 + a6 + a7;
        float* d = sums + (size_t)g * DIM + c * 4;
        atomicAdd(d + 0, a0[0]);
        atomicAdd(d + 1, a0[1]);
        atomicAdd(d + 2, a0[2]);
        atomicAdd(d + 3, a0[3]);
        cur = send;
    }
}

// ---------------------------------------------------------------------------
// K2: gemm1 split-K. grid (4 col x 64 row x 4 kslice) = 1024 blocks.
// Mean-fold applied to the partial (linear); atomics into zeroed h1raw.
// ---------------------------------------------------------------------------
__global__ __launch_bounds__(256) void gemm1_sk_kernel(const float* __restrict__ S,
                                                       const int* __restrict__ bi,
                                                       const float* __restrict__ W1,
                                                       float* __restrict__ h1raw,
                                                       int n_nodes) {
    const int col = blockIdx.x * 256 + threadIdx.x;
    const int r0 = blockIdx.y * 8;
    const int k0 = blockIdx.z * 128;
    __shared__ int sb[9];
    if (threadIdx.x < 9) {
        int v = r0 + (int)threadIdx.x;
        int lo = 0, hi = n_nodes;
        while (lo < hi) {
            int mid = (lo + hi) >> 1;
            if (bi[mid] < v) lo = mid + 1; else hi = mid;
        }
        sb[threadIdx.x] = lo;
    }
    __syncthreads();
    float inv[8];
#pragma unroll
    for (int r = 0; r < 8; ++r) {
        int cnt = sb[r + 1] - sb[r];
        inv[r] = 1.0f / (float)(cnt > 0 ? cnt : 1);
    }
    float acc[8] = {0,0,0,0,0,0,0,0};
#pragma unroll 8
    for (int k = k0; k < k0 + 128; ++k) {
        float w = W1[(size_t)k * DIM2 + col];
#pragma unroll
        for (int r = 0; r < 8; ++r)
            acc[r] += S[(size_t)(r0 + r) * DIM + k] * w;
    }
#pragma unroll
    for (int r = 0; r < 8; ++r)
        atomicAdd(&h1raw[(size_t)(r0 + r) * DIM2 + col], acc[r] * inv[r]);
}

// ---------------------------------------------------------------------------
// K3: gemm2 split-K with bias+ReLU fused into the operand load:
//   acc[r] += relu(h1raw[r][k] + b1[k]) * W2[k][col]
// (h1raw row + b1 are block-uniform -> scalar path). grid (2 x 64 x 8).
// ---------------------------------------------------------------------------
__global__ __launch_bounds__(256) void gemm2_sk_kernel(const float* __restrict__ h1raw,
                                                       const float* __restrict__ b1,
                                                       const float* __restrict__ W2,
                                                       float* __restrict__ h2raw) {
    const int col = blockIdx.x * 256 + threadIdx.x;
    const int r0 = blockIdx.y * 8;
    const int k0 = blockIdx.z * 128;
    float acc[8] = {0,0,0,0,0,0,0,0};
#pragma unroll 8
    for (int k = k0; k < k0 + 128; ++k) {
        float w = W2[(size_t)k * DIM + col];
        float bk = b1[k];
#pragma unroll
        for (int r = 0; r < 8; ++r) {
            float h = h1raw[(size_t)(r0 + r) * DIM2 + k] + bk;
            h = h > 0.0f ? h : 0.0f;
            acc[r] += h * w;
        }
    }
#pragma unroll
    for (int r = 0; r < 8; ++r)
        atomicAdd(&h2raw[(size_t)(r0 + r) * DIM + col], acc[r]);
}

// ---------------------------------------------------------------------------
// K4: LayerNorm of (h2raw + b2) -> hvn (d_out tail). 64 blocks x 512 thr.
// ---------------------------------------------------------------------------
__global__ __launch_bounds__(512) void ln_kernel(const float* __restrict__ h2raw,
                                                 const float* __restrict__ b2,
                                                 const float* __restrict__ gamma,
                                                 const float* __restrict__ beta,
                                                 float* __restrict__ hvn) {
    const int t = threadIdx.x;
    const int r0 = blockIdx.x * 8;
    float bb = b2[t];
    float v[8];
#pragma unroll
    for (int r = 0; r < 8; ++r) v[r] = h2raw[(size_t)(r0 + r) * DIM + t] + bb;

    __shared__ float sh_s[8][8], sh_ss[8][8];
    const int wid = t >> 6, lane = t & 63;
#pragma unroll
    for (int r = 0; r < 8; ++r) {
        float s = v[r], ss = v[r] * v[r];
#pragma unroll
        for (int off = 32; off > 0; off >>= 1) {
            s  += __shfl_xor(s,  off);
            ss += __shfl_xor(ss, off);
        }
        if (lane == 0) { sh_s[r][wid] = s; sh_ss[r][wid] = ss; }
    }
    __syncthreads();
    float gm = gamma[t], bt = beta[t];
#pragma unroll
    for (int r = 0; r < 8; ++r) {
        float s = 0.f, ss = 0.f;
#pragma unroll
        for (int w = 0; w < 8; ++w) { s += sh_s[r][w]; ss += sh_ss[r][w]; }
        float mu  = s * (1.0f / DIM);
        float var = ss * (1.0f / DIM) - mu * mu;
        float rs  = rsqrtf(var + LN_EPS);
        hvn[(size_t)(r0 + r) * DIM + t] = (v[r] - mu) * rs * gm + bt;
    }
}

// ---------------------------------------------------------------------------
// K5: x_new = x + hvn[batch_idx], run-structured. bi chunk in LDS; per
// graph-run the hv value is LOADED ONCE into a register and reused across
// all rows of the run (2 VMEM ops per f4: x-load + NT store). 8 x-loads
// in flight per lane; ~48 VGPR -> 8 waves/SIMD.
// ---------------------------------------------------------------------------
__global__ __launch_bounds__(TPB) void resid_kernel(const f4* __restrict__ x4,
                                                    const int* __restrict__ bi,
                                                    const f4* __restrict__ hv4,
                                                    f4* __restrict__ out4,
                                                    int n_nodes, int rpb) {
    __shared__ int bis[RPBMAX];
    const int blk = blockIdx.x, t = threadIdx.x;
    const int r0 = blk * rpb;
    const int r1 = min(n_nodes, r0 + rpb);
    const int n = r1 - r0;
    if (n <= 0) return;
    for (int i = t; i < n; i += TPB) bis[i] = bi[r0 + i];
    __syncthreads();

    const int par = t >> 7, c = t & 127;
    int cur = 0;
    while (cur < n) {
        const int g = bis[cur];
        int lo = cur + 1, hi = n;
        while (lo < hi) {
            int mid = (lo + hi) >> 1;
            if (bis[mid] <= g) lo = mid + 1; else hi = mid;
        }
        const int send = lo;
        const f4 hvreg = hv4[(size_t)g * 128 + c];   // once per run

        int r = cur;
        for (; r + 16 <= send; r += 16) {
            const size_t b = (size_t)(r0 + r + par) * 128 + c;
            f4 v0 = x4[b];        f4 v1 = x4[b + 256];
            f4 v2 = x4[b + 512];  f4 v3 = x4[b + 768];
            f4 v4 = x4[b + 1024]; f4 v5 = x4[b + 1280];
            f4 v6 = x4[b + 1536]; f4 v7 = x4[b + 1792];
            nts(out4 + b,        v0 + hvreg);
            nts(out4 + b + 256,  v1 + hvreg);
            nts(out4 + b + 512,  v2 + hvreg);
            nts(out4 + b + 768,  v3 + hvreg);
            nts(out4 + b + 1024, v4 + hvreg);
            nts(out4 + b + 1280, v5 + hvreg);
            nts(out4 + b + 1536, v6 + hvreg);
            nts(out4 + b + 1792, v7 + hvreg);
        }
        for (int rr = r + par; rr < send; rr += 2) {
            const size_t b = (size_t)(r0 + rr) * 128 + c;
            nts(out4 + b, x4[b] + hvreg);
        }
        cur = send;
    }
}

extern "C" void kernel_launch(void* const* d_in, const int* in_sizes, int n_in,
                              void* d_out, int out_size, void* d_ws, size_t ws_size,
                              hipStream_t stream) {
    const f4*    x4    = (const f4*)d_in[0];
    const int*   bidx  = (const int*)d_in[1];   // int32 per harness contract
    const float* W1    = (const float*)d_in[2];
    const float* b1    = (const float*)d_in[3];
    const float* W2    = (const float*)d_in[4];
    const float* b2    = (const float*)d_in[5];
    const float* gamma = (const float*)d_in[6];
    const float* beta  = (const float*)d_in[7];

    const int n_nodes = in_sizes[1];
    const size_t x_elems = (size_t)n_nodes * DIM;

    float* out   = (float*)d_out;
    f4*    xnew4 = (f4*)out;                  // output 0: [n_nodes, 512]
    float* hvn   = out + x_elems;             // output 1: [512, 512]

    // workspace: sums(1MB) | h1raw(4MB) | h2raw(1MB) — all atomic accumulators
    float* sums  = (float*)d_ws;
    float* h1raw = sums  + (size_t)NGRAPH * DIM;
    float* h2raw = h1raw + (size_t)NGRAPH * DIM2;

    int rpb = (n_nodes + NB - 1) / NB;
    if (rpb > RPBMAX - 1) rpb = RPBMAX - 1;   // safety (not hit at n=200000)
    const int nb = (n_nodes + rpb - 1) / rpb;

    hipMemsetAsync(sums, 0,
                   (size_t)(NGRAPH * DIM + NGRAPH * DIM2 + NGRAPH * DIM) * sizeof(float),
                   stream);
    segsum_kernel<<<nb, TPB, 0, stream>>>(x4, bidx, sums, n_nodes, rpb);
    gemm1_sk_kernel<<<dim3(4, 64, 4), 256, 0, stream>>>(sums, bidx, W1, h1raw, n_nodes);
    gemm2_sk_kernel<<<dim3(2, 64, 8), 256, 0, stream>>>(h1raw, b1, W2, h2raw);
    ln_kernel<<<64, 512, 0, stream>>>(h2raw, b2, gamma, beta, hvn);
    resid_kernel<<<nb, TPB, 0, stream>>>(x4, bidx, (const f4*)hvn, xnew4,
                                         n_nodes, rpb);
}

// Round 11
// 283.893 us; speedup vs baseline: 1.1047x; 1.1047x over previous
//
#include <hip/hip_runtime.h>

#define DIM 512
#define DIM2 1024
#define NGRAPH 512
#define LN_EPS 1e-5f
#define TPB 256
#define NB 2048      // chunk count for segsum/resid; rpb = ceil(200000/2048) = 98
#define RPBMAX 257   // LDS bi-cache capacity

typedef float f4 __attribute__((ext_vector_type(4)));

__device__ __forceinline__ void nts(f4* p, f4 v) { __builtin_nontemporal_store(v, p); }

// ---------------------------------------------------------------------------
// K1: segment sums. LDS bi-prefetch (search hits LDS broadcast), branchless
// 16-row inner loop (8 independent 16B loads/lane), pair-combine of the two
// row-parities in LDS before the atomic flush (halves atomics).
// Cached x reads seed L3 for the residual pass.
// ---------------------------------------------------------------------------
__global__ __launch_bounds__(TPB) void segsum_kernel(const f4* __restrict__ x4,
                                                     const int* __restrict__ bi,
                                                     float* __restrict__ sums,
                                                     int n_nodes, int rpb) {
    __shared__ int bis[RPBMAX];
    __shared__ f4 redbuf[128];
    const int blk = blockIdx.x, t = threadIdx.x;
    const int r0 = blk * rpb;
    const int r1 = min(n_nodes, r0 + rpb);
    const int n = r1 - r0;
    if (n <= 0) return;
    for (int i = t; i < n; i += TPB) bis[i] = bi[r0 + i];
    __syncthreads();

    const int par = t >> 7, c = t & 127;   // 2 rows x 128 f4-cols
    int cur = 0;
    while (cur < n) {
        const int g = bis[cur];
        int lo = cur + 1, hi = n;
        while (lo < hi) {                   // run end via LDS (broadcast)
            int mid = (lo + hi) >> 1;
            if (bis[mid] <= g) lo = mid + 1; else hi = mid;
        }
        const int send = lo;

        f4 a0={0,0,0,0}, a1={0,0,0,0}, a2={0,0,0,0}, a3={0,0,0,0};
        f4 a4={0,0,0,0}, a5={0,0,0,0}, a6={0,0,0,0}, a7={0,0,0,0};
        int r = cur;
        for (; r + 16 <= send; r += 16) {
            const size_t b = (size_t)(r0 + r + par) * 128 + c;
            f4 v0 = x4[b];        f4 v1 = x4[b + 256];
            f4 v2 = x4[b + 512];  f4 v3 = x4[b + 768];
            f4 v4 = x4[b + 1024]; f4 v5 = x4[b + 1280];
            f4 v6 = x4[b + 1536]; f4 v7 = x4[b + 1792];
            a0 += v0; a1 += v1; a2 += v2; a3 += v3;
            a4 += v4; a5 += v5; a6 += v6; a7 += v7;
        }
        for (int rr = r + par; rr < send; rr += 2)
            a0 += x4[(size_t)(r0 + rr) * 128 + c];

        a0 += a1 + a2 + a3 + a4 + a5 + a6 + a7;

        // pair-combine parities, single flush by par==0 threads
        if (par) redbuf[c] = a0;
        __syncthreads();
        if (!par) {
            a0 += redbuf[c];
            float* d = sums + (size_t)g * DIM + c * 4;
            atomicAdd(d + 0, a0[0]);
            atomicAdd(d + 1, a0[1]);
            atomicAdd(d + 2, a0[2]);
            atomicAdd(d + 3, a0[3]);
        }
        __syncthreads();                    // redbuf WAR before next run
        cur = send;
    }
}

// ---------------------------------------------------------------------------
// K2: gemm1 split-K, ATOMIC-FREE. grid (4 col x 64 row x 4 kslice).
// Each slice writes its own partial plane h1part[z][row][col] (plain
// stores, L2/L3-resident). Mean-fold applied per-partial (linear).
// ---------------------------------------------------------------------------
__global__ __launch_bounds__(256) void gemm1_sk_kernel(const float* __restrict__ S,
                                                       const int* __restrict__ bi,
                                                       const float* __restrict__ W1,
                                                       float* __restrict__ h1part,
                                                       int n_nodes) {
    const int col = blockIdx.x * 256 + threadIdx.x;
    const int r0 = blockIdx.y * 8;
    const int z = blockIdx.z;
    const int k0 = z * 128;
    __shared__ int sb[9];
    if (threadIdx.x < 9) {
        int v = r0 + (int)threadIdx.x;
        int lo = 0, hi = n_nodes;
        while (lo < hi) {
            int mid = (lo + hi) >> 1;
            if (bi[mid] < v) lo = mid + 1; else hi = mid;
        }
        sb[threadIdx.x] = lo;
    }
    __syncthreads();
    float inv[8];
#pragma unroll
    for (int r = 0; r < 8; ++r) {
        int cnt = sb[r + 1] - sb[r];
        inv[r] = 1.0f / (float)(cnt > 0 ? cnt : 1);
    }
    float acc[8] = {0,0,0,0,0,0,0,0};
#pragma unroll 8
    for (int k = k0; k < k0 + 128; ++k) {
        float w = W1[(size_t)k * DIM2 + col];
#pragma unroll
        for (int r = 0; r < 8; ++r)
            acc[r] += S[(size_t)(r0 + r) * DIM + k] * w;
    }
    float* dst = h1part + ((size_t)z * NGRAPH + r0) * DIM2 + col;
#pragma unroll
    for (int r = 0; r < 8; ++r)
        dst[(size_t)r * DIM2] = acc[r] * inv[r];
}

// ---------------------------------------------------------------------------
// K3: h1act = relu(sum_z h1part[z] + b1). f4-vectorized slice reduction.
// ---------------------------------------------------------------------------
__global__ __launch_bounds__(256) void bias_relu_kernel(const f4* __restrict__ h1part,
                                                        const float* __restrict__ b1,
                                                        f4* __restrict__ h1act) {
    const int i = blockIdx.x * 256 + threadIdx.x;   // over 512*1024/4
    const int SL = NGRAPH * DIM2 / 4;               // f4 per slice
    f4 v = h1part[i] + h1part[i + SL] + h1part[i + 2 * SL] + h1part[i + 3 * SL];
    const f4 bb = *(const f4*)&b1[(i & (DIM2 / 4 - 1)) * 4];
    v += bb;
#pragma unroll
    for (int j = 0; j < 4; ++j) v[j] = v[j] > 0.0f ? v[j] : 0.0f;
    h1act[i] = v;
}

// ---------------------------------------------------------------------------
// K4: gemm2 split-K, ATOMIC-FREE. grid (2 col x 64 row x 8 kslice);
// partials into h2part[z][row][col] (plain stores).
// ---------------------------------------------------------------------------
__global__ __launch_bounds__(256) void gemm2_sk_kernel(const float* __restrict__ h1act,
                                                       const float* __restrict__ W2,
                                                       float* __restrict__ h2part) {
    const int col = blockIdx.x * 256 + threadIdx.x;
    const int r0 = blockIdx.y * 8;
    const int z = blockIdx.z;
    const int k0 = z * 128;
    float acc[8] = {0,0,0,0,0,0,0,0};
#pragma unroll 8
    for (int k = k0; k < k0 + 128; ++k) {
        float w = W2[(size_t)k * DIM + col];
#pragma unroll
        for (int r = 0; r < 8; ++r)
            acc[r] += h1act[(size_t)(r0 + r) * DIM2 + k] * w;
    }
    float* dst = h2part + ((size_t)z * NGRAPH + r0) * DIM + col;
#pragma unroll
    for (int r = 0; r < 8; ++r)
        dst[(size_t)r * DIM] = acc[r];
}

// ---------------------------------------------------------------------------
// K5: LayerNorm of (sum_z h2part[z] + b2) -> hvn. 64 blocks x 512 thr.
// ---------------------------------------------------------------------------
__global__ __launch_bounds__(512) void ln_kernel(const float* __restrict__ h2part,
                                                 const float* __restrict__ b2,
                                                 const float* __restrict__ gamma,
                                                 const float* __restrict__ beta,
                                                 float* __restrict__ hvn) {
    const int t = threadIdx.x;
    const int r0 = blockIdx.x * 8;
    const float bb = b2[t];
    float v[8];
#pragma unroll
    for (int r = 0; r < 8; ++r) {
        float s = bb;
#pragma unroll
        for (int z = 0; z < 8; ++z)
            s += h2part[((size_t)z * NGRAPH + r0 + r) * DIM + t];
        v[r] = s;
    }

    __shared__ float sh_s[8][8], sh_ss[8][8];
    const int wid = t >> 6, lane = t & 63;
#pragma unroll
    for (int r = 0; r < 8; ++r) {
        float s = v[r], ss = v[r] * v[r];
#pragma unroll
        for (int off = 32; off > 0; off >>= 1) {
            s  += __shfl_xor(s,  off);
            ss += __shfl_xor(ss, off);
        }
        if (lane == 0) { sh_s[r][wid] = s; sh_ss[r][wid] = ss; }
    }
    __syncthreads();
    float gm = gamma[t], bt = beta[t];
#pragma unroll
    for (int r = 0; r < 8; ++r) {
        float s = 0.f, ss = 0.f;
#pragma unroll
        for (int w = 0; w < 8; ++w) { s += sh_s[r][w]; ss += sh_ss[r][w]; }
        float mu  = s * (1.0f / DIM);
        float var = ss * (1.0f / DIM) - mu * mu;
        float rs  = rsqrtf(var + LN_EPS);
        hvn[(size_t)(r0 + r) * DIM + t] = (v[r] - mu) * rs * gm + bt;
    }
}

// ---------------------------------------------------------------------------
// K6: x_new = x + hvn[batch_idx] — EXACT R9 version (16-deep independent
// pipeline: 16 x-loads, 16 hv gathers, 16 NT stores). Reverse macro-order.
// ---------------------------------------------------------------------------
__global__ __launch_bounds__(TPB) void resid_kernel(const f4* __restrict__ x4,
                                                    const int* __restrict__ bi,
                                                    const f4* __restrict__ hv4,
                                                    f4* __restrict__ out4,
                                                    int n_nodes, int rpb) {
    const int blk = blockIdx.x, t = threadIdx.x;
    const int r0 = blk * rpb;
    const int r1 = min(n_nodes, r0 + rpb);
    if (r0 >= r1) return;
    const int base = r0 * 128, endi = r1 * 128;
    const int gsz = TPB * 16;
    const int ngrp = (endi - base + gsz - 1) / gsz;

    for (int gi = ngrp - 1; gi >= 0; --gi) {
        const int gb = base + gi * gsz;
        if (gb + gsz <= endi) {
            const int j = gb + t;
            f4 xv[16];
#pragma unroll
            for (int k = 0; k < 16; ++k) xv[k] = x4[j + k * TPB];
            f4 hv[16];
#pragma unroll
            for (int k = 0; k < 16; ++k) {
                const int jj = j + k * TPB;
                hv[k] = hv4[(bi[jj >> 7] << 7) + (jj & 127)];
            }
#pragma unroll
            for (int k = 0; k < 16; ++k) nts(out4 + j + k * TPB, xv[k] + hv[k]);
        } else {
            for (int j = gb + t; j < endi; j += TPB) {
                f4 xv = x4[j];
                int g = bi[j >> 7];
                nts(out4 + j, xv + hv4[(g << 7) + (j & 127)]);
            }
        }
    }
}

extern "C" void kernel_launch(void* const* d_in, const int* in_sizes, int n_in,
                              void* d_out, int out_size, void* d_ws, size_t ws_size,
                              hipStream_t stream) {
    const f4*    x4    = (const f4*)d_in[0];
    const int*   bidx  = (const int*)d_in[1];   // int32 per harness contract
    const float* W1    = (const float*)d_in[2];
    const float* b1    = (const float*)d_in[3];
    const float* W2    = (const float*)d_in[4];
    const float* b2    = (const float*)d_in[5];
    const float* gamma = (const float*)d_in[6];
    const float* beta  = (const float*)d_in[7];

    const int n_nodes = in_sizes[1];
    const size_t x_elems = (size_t)n_nodes * DIM;

    float* out   = (float*)d_out;
    f4*    xnew4 = (f4*)out;                  // output 0: [n_nodes, 512]
    float* hvn   = out + x_elems;             // output 1: [512, 512]

    // workspace: sums(1MB) | h1act(2MB) | bigbuf(8MB: h1part then h2part)
    float* sums   = (float*)d_ws;
    float* h1act  = sums + (size_t)NGRAPH * DIM;
    float* bigbuf = h1act + (size_t)NGRAPH * DIM2;
    float* h1part = bigbuf;                   // 4 x 512 x 1024
    float* h2part = bigbuf;                   // 8 x 512 x 512 (after h1part dead)

    int rpb = (n_nodes + NB - 1) / NB;
    if (rpb > RPBMAX - 1) rpb = RPBMAX - 1;
    const int nb = (n_nodes + rpb - 1) / rpb;

    hipMemsetAsync(sums, 0, (size_t)NGRAPH * DIM * sizeof(float), stream);
    segsum_kernel<<<nb, TPB, 0, stream>>>(x4, bidx, sums, n_nodes, rpb);
    gemm1_sk_kernel<<<dim3(4, 64, 4), 256, 0, stream>>>(sums, bidx, W1, h1part, n_nodes);
    bias_relu_kernel<<<(NGRAPH * DIM2 / 4) / 256, 256, 0, stream>>>((const f4*)h1part,
                                                                    b1, (f4*)h1act);
    gemm2_sk_kernel<<<dim3(2, 64, 8), 256, 0, stream>>>(h1act, W2, h2part);
    ln_kernel<<<64, 512, 0, stream>>>(h2part, b2, gamma, beta, hvn);
    resid_kernel<<<nb, TPB, 0, stream>>>(x4, bidx, (const f4*)hvn, xnew4,
                                         n_nodes, rpb);
}

// Round 12
// 272.702 us; speedup vs baseline: 1.1500x; 1.0410x over previous
//
#include <hip/hip_runtime.h>

#define DIM 512
#define DIM2 1024
#define NGRAPH 512
#define LN_EPS 1e-5f
#define TPB 256
#define NB 2048      // chunk count for segsum/resid; rpb = ceil(200000/2048) = 98
#define RPBMAX 257   // LDS bi-cache capacity

typedef float f4 __attribute__((ext_vector_type(4)));

__device__ __forceinline__ void nts(f4* p, f4 v) { __builtin_nontemporal_store(v, p); }

// ---------------------------------------------------------------------------
// K1: segment sums (R11, unchanged). LDS bi-prefetch, branchless 16-row
// inner loop, parity pair-combine before atomic flush. Cached x reads
// deliberately seed L3 for the residual pass.
// ---------------------------------------------------------------------------
__global__ __launch_bounds__(TPB) void segsum_kernel(const f4* __restrict__ x4,
                                                     const int* __restrict__ bi,
                                                     float* __restrict__ sums,
                                                     int n_nodes, int rpb) {
    __shared__ int bis[RPBMAX];
    __shared__ f4 redbuf[128];
    const int blk = blockIdx.x, t = threadIdx.x;
    const int r0 = blk * rpb;
    const int r1 = min(n_nodes, r0 + rpb);
    const int n = r1 - r0;
    if (n <= 0) return;
    for (int i = t; i < n; i += TPB) bis[i] = bi[r0 + i];
    __syncthreads();

    const int par = t >> 7, c = t & 127;   // 2 rows x 128 f4-cols
    int cur = 0;
    while (cur < n) {
        const int g = bis[cur];
        int lo = cur + 1, hi = n;
        while (lo < hi) {                   // run end via LDS (broadcast)
            int mid = (lo + hi) >> 1;
            if (bis[mid] <= g) lo = mid + 1; else hi = mid;
        }
        const int send = lo;

        f4 a0={0,0,0,0}, a1={0,0,0,0}, a2={0,0,0,0}, a3={0,0,0,0};
        f4 a4={0,0,0,0}, a5={0,0,0,0}, a6={0,0,0,0}, a7={0,0,0,0};
        int r = cur;
        for (; r + 16 <= send; r += 16) {
            const size_t b = (size_t)(r0 + r + par) * 128 + c;
            f4 v0 = x4[b];        f4 v1 = x4[b + 256];
            f4 v2 = x4[b + 512];  f4 v3 = x4[b + 768];
            f4 v4 = x4[b + 1024]; f4 v5 = x4[b + 1280];
            f4 v6 = x4[b + 1536]; f4 v7 = x4[b + 1792];
            a0 += v0; a1 += v1; a2 += v2; a3 += v3;
            a4 += v4; a5 += v5; a6 += v6; a7 += v7;
        }
        for (int rr = r + par; rr < send; rr += 2)
            a0 += x4[(size_t)(r0 + rr) * 128 + c];

        a0 += a1 + a2 + a3 + a4 + a5 + a6 + a7;

        if (par) redbuf[c] = a0;
        __syncthreads();
        if (!par) {
            a0 += redbuf[c];
            float* d = sums + (size_t)g * DIM + c * 4;
            atomicAdd(d + 0, a0[0]);
            atomicAdd(d + 1, a0[1]);
            atomicAdd(d + 2, a0[2]);
            atomicAdd(d + 3, a0[3]);
        }
        __syncthreads();
        cur = send;
    }
}

// ---------------------------------------------------------------------------
// K2: gemm1 split-K, atomic-free (R11, unchanged).
// ---------------------------------------------------------------------------
__global__ __launch_bounds__(256) void gemm1_sk_kernel(const float* __restrict__ S,
                                                       const int* __restrict__ bi,
                                                       const float* __restrict__ W1,
                                                       float* __restrict__ h1part,
                                                       int n_nodes) {
    const int col = blockIdx.x * 256 + threadIdx.x;
    const int r0 = blockIdx.y * 8;
    const int z = blockIdx.z;
    const int k0 = z * 128;
    __shared__ int sb[9];
    if (threadIdx.x < 9) {
        int v = r0 + (int)threadIdx.x;
        int lo = 0, hi = n_nodes;
        while (lo < hi) {
            int mid = (lo + hi) >> 1;
            if (bi[mid] < v) lo = mid + 1; else hi = mid;
        }
        sb[threadIdx.x] = lo;
    }
    __syncthreads();
    float inv[8];
#pragma unroll
    for (int r = 0; r < 8; ++r) {
        int cnt = sb[r + 1] - sb[r];
        inv[r] = 1.0f / (float)(cnt > 0 ? cnt : 1);
    }
    float acc[8] = {0,0,0,0,0,0,0,0};
#pragma unroll 8
    for (int k = k0; k < k0 + 128; ++k) {
        float w = W1[(size_t)k * DIM2 + col];
#pragma unroll
        for (int r = 0; r < 8; ++r)
            acc[r] += S[(size_t)(r0 + r) * DIM + k] * w;
    }
    float* dst = h1part + ((size_t)z * NGRAPH + r0) * DIM2 + col;
#pragma unroll
    for (int r = 0; r < 8; ++r)
        dst[(size_t)r * DIM2] = acc[r] * inv[r];
}

// ---------------------------------------------------------------------------
// K3: h1act = relu(sum_z h1part[z] + b1) (R11, unchanged).
// ---------------------------------------------------------------------------
__global__ __launch_bounds__(256) void bias_relu_kernel(const f4* __restrict__ h1part,
                                                        const float* __restrict__ b1,
                                                        f4* __restrict__ h1act) {
    const int i = blockIdx.x * 256 + threadIdx.x;
    const int SL = NGRAPH * DIM2 / 4;
    f4 v = h1part[i] + h1part[i + SL] + h1part[i + 2 * SL] + h1part[i + 3 * SL];
    const f4 bb = *(const f4*)&b1[(i & (DIM2 / 4 - 1)) * 4];
    v += bb;
#pragma unroll
    for (int j = 0; j < 4; ++j) v[j] = v[j] > 0.0f ? v[j] : 0.0f;
    h1act[i] = v;
}

// ---------------------------------------------------------------------------
// K4: gemm2 split-K, atomic-free (R11, unchanged).
// ---------------------------------------------------------------------------
__global__ __launch_bounds__(256) void gemm2_sk_kernel(const float* __restrict__ h1act,
                                                       const float* __restrict__ W2,
                                                       float* __restrict__ h2part) {
    const int col = blockIdx.x * 256 + threadIdx.x;
    const int r0 = blockIdx.y * 8;
    const int z = blockIdx.z;
    const int k0 = z * 128;
    float acc[8] = {0,0,0,0,0,0,0,0};
#pragma unroll 8
    for (int k = k0; k < k0 + 128; ++k) {
        float w = W2[(size_t)k * DIM + col];
#pragma unroll
        for (int r = 0; r < 8; ++r)
            acc[r] += h1act[(size_t)(r0 + r) * DIM2 + k] * w;
    }
    float* dst = h2part + ((size_t)z * NGRAPH + r0) * DIM + col;
#pragma unroll
    for (int r = 0; r < 8; ++r)
        dst[(size_t)r * DIM] = acc[r];
}

// ---------------------------------------------------------------------------
// K5: LayerNorm of (sum_z h2part[z] + b2) -> hvn (R11, unchanged).
// ---------------------------------------------------------------------------
__global__ __launch_bounds__(512) void ln_kernel(const float* __restrict__ h2part,
                                                 const float* __restrict__ b2,
                                                 const float* __restrict__ gamma,
                                                 const float* __restrict__ beta,
                                                 float* __restrict__ hvn) {
    const int t = threadIdx.x;
    const int r0 = blockIdx.x * 8;
    const float bb = b2[t];
    float v[8];
#pragma unroll
    for (int r = 0; r < 8; ++r) {
        float s = bb;
#pragma unroll
        for (int z = 0; z < 8; ++z)
            s += h2part[((size_t)z * NGRAPH + r0 + r) * DIM + t];
        v[r] = s;
    }

    __shared__ float sh_s[8][8], sh_ss[8][8];
    const int wid = t >> 6, lane = t & 63;
#pragma unroll
    for (int r = 0; r < 8; ++r) {
        float s = v[r], ss = v[r] * v[r];
#pragma unroll
        for (int off = 32; off > 0; off >>= 1) {
            s  += __shfl_xor(s,  off);
            ss += __shfl_xor(ss, off);
        }
        if (lane == 0) { sh_s[r][wid] = s; sh_ss[r][wid] = ss; }
    }
    __syncthreads();
    float gm = gamma[t], bt = beta[t];
#pragma unroll
    for (int r = 0; r < 8; ++r) {
        float s = 0.f, ss = 0.f;
#pragma unroll
        for (int w = 0; w < 8; ++w) { s += sh_s[r][w]; ss += sh_ss[r][w]; }
        float mu  = s * (1.0f / DIM);
        float var = ss * (1.0f / DIM) - mu * mu;
        float rs  = rsqrtf(var + LN_EPS);
        hvn[(size_t)(r0 + r) * DIM + t] = (v[r] - mu) * rs * gm + bt;
    }
}

// ---------------------------------------------------------------------------
// K6: x_new = x + hvn[batch_idx]. R11's 16-deep pipeline, ONE change:
// chunk assignment is REVERSED across blocks (block b -> chunk nb-1-b).
// First-dispatched blocks re-read the tail of x — the part segsum read
// most recently, still L3-resident — before it gets evicted.
// ---------------------------------------------------------------------------
__global__ __launch_bounds__(TPB) void resid_kernel(const f4* __restrict__ x4,
                                                    const int* __restrict__ bi,
                                                    const f4* __restrict__ hv4,
                                                    f4* __restrict__ out4,
                                                    int n_nodes, int rpb) {
    const int nb = gridDim.x;
    const int blk = (nb - 1) - blockIdx.x;        // <<< reversed chunk map
    const int t = threadIdx.x;
    const int r0 = blk * rpb;
    const int r1 = min(n_nodes, r0 + rpb);
    if (r0 >= r1) return;
    const int base = r0 * 128, endi = r1 * 128;
    const int gsz = TPB * 16;
    const int ngrp = (endi - base + gsz - 1) / gsz;

    for (int gi = ngrp - 1; gi >= 0; --gi) {
        const int gb = base + gi * gsz;
        if (gb + gsz <= endi) {
            const int j = gb + t;
            f4 xv[16];
#pragma unroll
            for (int k = 0; k < 16; ++k) xv[k] = x4[j + k * TPB];
            f4 hv[16];
#pragma unroll
            for (int k = 0; k < 16; ++k) {
                const int jj = j + k * TPB;
                hv[k] = hv4[(bi[jj >> 7] << 7) + (jj & 127)];
            }
#pragma unroll
            for (int k = 0; k < 16; ++k) nts(out4 + j + k * TPB, xv[k] + hv[k]);
        } else {
            for (int j = gb + t; j < endi; j += TPB) {
                f4 xv = x4[j];
                int g = bi[j >> 7];
                nts(out4 + j, xv + hv4[(g << 7) + (j & 127)]);
            }
        }
    }
}

extern "C" void kernel_launch(void* const* d_in, const int* in_sizes, int n_in,
                              void* d_out, int out_size, void* d_ws, size_t ws_size,
                              hipStream_t stream) {
    const f4*    x4    = (const f4*)d_in[0];
    const int*   bidx  = (const int*)d_in[1];   // int32 per harness contract
    const float* W1    = (const float*)d_in[2];
    const float* b1    = (const float*)d_in[3];
    const float* W2    = (const float*)d_in[4];
    const float* b2    = (const float*)d_in[5];
    const float* gamma = (const float*)d_in[6];
    const float* beta  = (const float*)d_in[7];

    const int n_nodes = in_sizes[1];
    const size_t x_elems = (size_t)n_nodes * DIM;

    float* out   = (float*)d_out;
    f4*    xnew4 = (f4*)out;                  // output 0: [n_nodes, 512]
    float* hvn   = out + x_elems;             // output 1: [512, 512]

    // workspace: sums(1MB) | h1act(2MB) | bigbuf(8MB: h1part then h2part)
    float* sums   = (float*)d_ws;
    float* h1act  = sums + (size_t)NGRAPH * DIM;
    float* bigbuf = h1act + (size_t)NGRAPH * DIM2;
    float* h1part = bigbuf;                   // 4 x 512 x 1024
    float* h2part = bigbuf;                   // 8 x 512 x 512 (h1part dead by then)

    int rpb = (n_nodes + NB - 1) / NB;
    if (rpb > RPBMAX - 1) rpb = RPBMAX - 1;
    const int nb = (n_nodes + rpb - 1) / rpb;

    hipMemsetAsync(sums, 0, (size_t)NGRAPH * DIM * sizeof(float), stream);
    segsum_kernel<<<nb, TPB, 0, stream>>>(x4, bidx, sums, n_nodes, rpb);
    gemm1_sk_kernel<<<dim3(4, 64, 4), 256, 0, stream>>>(sums, bidx, W1, h1part, n_nodes);
    bias_relu_kernel<<<(NGRAPH * DIM2 / 4) / 256, 256, 0, stream>>>((const f4*)h1part,
                                                                    b1, (f4*)h1act);
    gemm2_sk_kernel<<<dim3(2, 64, 8), 256, 0, stream>>>(h1act, W2, h2part);
    ln_kernel<<<64, 512, 0, stream>>>(h2part, b2, gamma, beta, hvn);
    resid_kernel<<<nb, TPB, 0, stream>>>(x4, bidx, (const f4*)hvn, xnew4,
                                         n_nodes, rpb);
}